// Round 4
// baseline (303.884 us; speedup 1.0000x reference)
//
#include <hip/hip_runtime.h>
#include <stdint.h>

// Problem constants (fixed by reference)
#define B_ROWS 8192
#define DH     1024      // D == H == 1024
#define KTOT   2048      // D + H (concatenated K)
#define NTOT   4096      // 4*H columns (gate-deinterleaved packing, see below)

typedef __attribute__((ext_vector_type(8))) __bf16 bf16x8;
typedef __attribute__((ext_vector_type(4))) float  f32x4;

// ---------- helpers ----------
__device__ __forceinline__ unsigned short f2bf(float f) {
    unsigned int u = __float_as_uint(f);
    u += 0x7FFFu + ((u >> 16) & 1u);   // round-to-nearest-even
    return (unsigned short)(u >> 16);
}

__device__ __forceinline__ float fast_sigmoid(float x) {
    return 1.0f / (1.0f + __expf(-x));
}
__device__ __forceinline__ float fast_tanh(float x) {
    float e = __expf(fminf(-2.0f * x, 80.0f));   // clamp avoids inf/inf
    return (1.0f - e) / (1.0f + e);
}

// ---------- single fused pack kernel ----------
// N-space packing (gate-deinterleaved for the shuffle-free epilogue):
//   W_cat row n holds W row g = gate*DH + h with
//     gate = (n>>4) & 3,  h = (n>>6)*16 + (n&15)
//   bias[] packed identically.  The GEMM is invariant to this column perm.
#define NBLK_A (B_ROWS)            // one block packs one 2048-elem row
#define NBLK_W (NTOT)
#define NBLK_BIAS (NTOT / 256)

__global__ __launch_bounds__(256) void pack_all(const float* __restrict__ e_t,
                                                const float* __restrict__ h_prev,
                                                const float* __restrict__ W_x,
                                                const float* __restrict__ W_h,
                                                const float* __restrict__ b_x,
                                                const float* __restrict__ b_h,
                                                const float* __restrict__ b_e,
                                                unsigned short* __restrict__ A_cat,
                                                unsigned short* __restrict__ W_cat,
                                                float* __restrict__ bias) {
    const int blk = blockIdx.x;
    const int t   = threadIdx.x;
    if (blk < NBLK_A + NBLK_W) {
        const float* src0;
        unsigned short* dst;
        int row;
        if (blk < NBLK_A) {
            row = blk;
            dst = A_cat + (size_t)row * KTOT;
            int c8 = t << 3;
            src0 = (c8 < DH) ? (e_t + (size_t)row * DH + c8)
                             : (h_prev + (size_t)row * DH + (c8 - DH));
        } else {
            row = blk - NBLK_A;                 // n in [0,4096)
            int gate = (row >> 4) & 3;
            int h    = (row >> 6) * 16 + (row & 15);
            int srow = gate * DH + h;
            dst = W_cat + (size_t)row * KTOT;
            int c8 = t << 3;
            src0 = (c8 < DH) ? (W_x + (size_t)srow * DH + c8)
                             : (W_h + (size_t)srow * DH + (c8 - DH));
        }
        float4 f0 = ((const float4*)src0)[0];
        float4 f1 = ((const float4*)src0)[1];
        uint4 o;
        o.x = (unsigned)f2bf(f0.x) | ((unsigned)f2bf(f0.y) << 16);
        o.y = (unsigned)f2bf(f0.z) | ((unsigned)f2bf(f0.w) << 16);
        o.z = (unsigned)f2bf(f1.x) | ((unsigned)f2bf(f1.y) << 16);
        o.w = (unsigned)f2bf(f1.z) | ((unsigned)f2bf(f1.w) << 16);
        *(uint4*)(dst + t * 8) = o;
    } else {
        int gp = (blk - NBLK_A - NBLK_W) * 256 + t;   // n in [0,4096)
        int gate = (gp >> 4) & 3;
        int h    = (gp >> 6) * 16 + (gp & 15);
        int g    = gate * DH + h;
        bias[gp] = b_x[g] + b_h[g] + b_e[g];
    }
}

// ---------- 256x256 8-wave GEMM, m201-faithful 4-phase schedule ----------
//
// BM=BN=256, BK=64, 8 waves (2M x 4N), LDS 128 KiB (2-parity A/B buffers).
// XOR granule swizzle (verified): logical 16B-granule g of row r stored at
// physical p = g ^ (r&7); applied on the global SOURCE address; fragment
// reads use p = (kk*4+quad) ^ (lane15&7).
//
// ROUND-4 RESTRUCTURE (the m201 phase recipe, correctly this time):
// clusters decomposed by (m-half, kk) -> per-phase reads {8,4,8,4}, each
// phase MFMAs a full 4-n sweep at fixed (m-half,kk).  Staging spread
// {2,2,0,4} GLL; ONE counted vmcnt(4) per K-tile.
//   P1: read A-lo-kk0(4)+B-kk0(4); stage A(t+1) h0 (2 GLL -> As_next)
//   P2: read A-hi-kk0(4);          stage A(t+1) h1 (2 GLL -> As_next)
//   P3: read A-lo-kk1(4)+B-kk1(4)
//   P4: read A-hi-kk1(4);          stage B(t+2)    (4 GLL -> Bs_cur);
//       after MFMA: vmcnt(4)  [per-wave GLL order B(t+1)4,A(t+1)4,B(t+2)4
//                              -> leaves only B(t+2) in flight]
// LIVENESS: B(t) last read in P3 -> B region free after P3's trailing
// barrier (every wave did lgkmcnt(0) in P3) -> P4 stage into Bs_cur safe.
// A(t) last read in P4 -> As_next (other parity) was freed at P4(t-1)'s
// trailing barrier -> P1/P2 stage safe.  vmcnt never 0 in the main loop.

#define GLL(srcp, dstp) \
    __builtin_amdgcn_global_load_lds( \
        (const __attribute__((address_space(1))) void*)(srcp), \
        (__attribute__((address_space(3))) void*)(dstp), 16, 0, 0)

// one half-tile = 128 rows x 64 cols bf16 = 2 GLL/wave (8 waves x 64 lanes x 16B)
#define STAGE_HALF(g, buf, h, kt) do { \
    GLL((g) + ((size_t)((h) * 128)      * KTOT) + (size_t)(kt) * 64, (buf) + (((h) * 128)      + w8) * 128); \
    GLL((g) + ((size_t)((h) * 128 + 64) * KTOT) + (size_t)(kt) * 64, (buf) + (((h) * 128 + 64) + w8) * 128); \
} while (0)

#define SB() __builtin_amdgcn_sched_barrier(0)

// phase sync: reads/stages pinned before barrier; drain own LDS reads after
#define PHASE_SYNC() do { \
    SB(); \
    __builtin_amdgcn_s_barrier(); \
    asm volatile("s_waitcnt lgkmcnt(0)" ::: "memory"); \
    SB(); \
} while (0)

#define PHASE_CLOSE() do { \
    SB(); \
    __builtin_amdgcn_s_barrier(); \
    SB(); \
} while (0)

template <int MODE>  // 2 = steady  (stage A(t+1) P1/P2, B(t+2) P4, vmcnt(4))
                     // 1 = tile 30 (stage A(31) P1/P2 only, vmcnt(0))
                     // 0 = tile 31 (no staging, no vmcnt)
__device__ __forceinline__ void do_tile(
    int kt,
    unsigned char* As_cur, unsigned char* As_next, unsigned char* Bs_cur,
    const unsigned short* __restrict__ gA, const unsigned short* __restrict__ gB,
    int w8, int rowA, int rowB, int xg0, int xg1,
    f32x4 (&acc)[8][4])
{
    bf16x8 al[4], b[4];

    // ================ phase 1: A-lo kk0 + B kk0; stage A(t+1) h0 ============
#pragma unroll
    for (int mi = 0; mi < 4; ++mi)
        al[mi] = *(const bf16x8*)(As_cur + rowA + mi * 2048 + xg0);
#pragma unroll
    for (int ni = 0; ni < 4; ++ni)
        b[ni] = *(const bf16x8*)(Bs_cur + rowB + ni * 2048 + xg0);
    if constexpr (MODE >= 1) STAGE_HALF(gA, As_next, 0, kt + 1);
    PHASE_SYNC();
    __builtin_amdgcn_s_setprio(1);
#pragma unroll
    for (int mi = 0; mi < 4; ++mi)
#pragma unroll
        for (int ni = 0; ni < 4; ++ni)
            acc[mi][ni] = __builtin_amdgcn_mfma_f32_16x16x32_bf16(al[mi], b[ni], acc[mi][ni], 0, 0, 0);
    __builtin_amdgcn_s_setprio(0);
    PHASE_CLOSE();

    // ================ phase 2: A-hi kk0; stage A(t+1) h1 ====================
    bf16x8 ah[4];
#pragma unroll
    for (int mi = 0; mi < 4; ++mi)
        ah[mi] = *(const bf16x8*)(As_cur + rowA + (4 + mi) * 2048 + xg0);
    if constexpr (MODE >= 1) STAGE_HALF(gA, As_next, 1, kt + 1);
    PHASE_SYNC();
    __builtin_amdgcn_s_setprio(1);
#pragma unroll
    for (int mi = 0; mi < 4; ++mi)
#pragma unroll
        for (int ni = 0; ni < 4; ++ni)
            acc[4 + mi][ni] = __builtin_amdgcn_mfma_f32_16x16x32_bf16(ah[mi], b[ni], acc[4 + mi][ni], 0, 0, 0);
    __builtin_amdgcn_s_setprio(0);
    PHASE_CLOSE();

    // ================ phase 3: A-lo kk1 + B kk1 =============================
#pragma unroll
    for (int mi = 0; mi < 4; ++mi)
        al[mi] = *(const bf16x8*)(As_cur + rowA + mi * 2048 + xg1);
#pragma unroll
    for (int ni = 0; ni < 4; ++ni)
        b[ni] = *(const bf16x8*)(Bs_cur + rowB + ni * 2048 + xg1);
    PHASE_SYNC();
    __builtin_amdgcn_s_setprio(1);
#pragma unroll
    for (int mi = 0; mi < 4; ++mi)
#pragma unroll
        for (int ni = 0; ni < 4; ++ni)
            acc[mi][ni] = __builtin_amdgcn_mfma_f32_16x16x32_bf16(al[mi], b[ni], acc[mi][ni], 0, 0, 0);
    __builtin_amdgcn_s_setprio(0);
    PHASE_CLOSE();   // <- all B(t) reads retired in every wave

    // ================ phase 4: A-hi kk1; stage B(t+2); vmcnt(4) =============
#pragma unroll
    for (int mi = 0; mi < 4; ++mi)
        ah[mi] = *(const bf16x8*)(As_cur + rowA + (4 + mi) * 2048 + xg1);
    if constexpr (MODE == 2) {
        STAGE_HALF(gB, Bs_cur, 0, kt + 2);
        STAGE_HALF(gB, Bs_cur, 1, kt + 2);
    }
    PHASE_SYNC();
    __builtin_amdgcn_s_setprio(1);
#pragma unroll
    for (int mi = 0; mi < 4; ++mi)
#pragma unroll
        for (int ni = 0; ni < 4; ++ni)
            acc[4 + mi][ni] = __builtin_amdgcn_mfma_f32_16x16x32_bf16(ah[mi], b[ni], acc[4 + mi][ni], 0, 0, 0);
    __builtin_amdgcn_s_setprio(0);
    SB();
    if constexpr (MODE == 2) {
        asm volatile("s_waitcnt vmcnt(4)" ::: "memory");   // tile t+1 resident
        SB();
    } else if constexpr (MODE == 1) {
        asm volatile("s_waitcnt vmcnt(0)" ::: "memory");   // tile 31 resident
        SB();
    }
    __builtin_amdgcn_s_barrier();
    SB();
}

__global__ __launch_bounds__(512, 2) void lstm_gemm(
    const unsigned short* __restrict__ A,
    const unsigned short* __restrict__ Wc,
    const float* __restrict__ bias,
    const float* __restrict__ c_prev,
    float* __restrict__ h_out,
    float* __restrict__ c_out)
{
    __shared__ __align__(16) unsigned char lds[131072];

    const int tid = threadIdx.x;
    const int w   = tid >> 6;          // wave 0..7
    const int l   = tid & 63;          // lane
    const int wm  = w >> 2, wn = w & 3;
    const int m0  = blockIdx.y * 256;
    const int n0  = blockIdx.x * 256;
    const int w8  = w * 8;

    f32x4 acc[8][4];
#pragma unroll
    for (int i = 0; i < 8; ++i)
#pragma unroll
        for (int j = 0; j < 4; ++j) acc[i][j] = {0.f, 0.f, 0.f, 0.f};

    // staging: wave w, lane l -> tile row = base + w*8 + (l>>3),
    // physical granule p = l&7, pre-swizzled source granule g = p ^ (row&7)
    const int srow = w8 + (l >> 3);
    const int scol = ((l & 7) ^ ((l >> 3) & 7)) * 8;   // element offset in 64-wide K-tile
    const unsigned short* gA = A  + (size_t)(m0 + srow) * KTOT + scol;
    const unsigned short* gB = Wc + (size_t)(n0 + srow) * KTOT + scol;

    unsigned char* As0 = lds;
    unsigned char* As1 = lds + 32768;
    unsigned char* Bs0 = lds + 65536;
    unsigned char* Bs1 = lds + 98304;

    const int lane15 = l & 15;
    const int quad   = l >> 4;
    const int rowA = (wm * 128 + lane15) * 128;   // byte offset of A fragment row base
    const int rowB = (wn * 64  + lane15) * 128;
    const int xg0  = ((0 + quad) ^ (lane15 & 7)) * 16;   // kk=0 swizzled granule
    const int xg1  = ((4 + quad) ^ (lane15 & 7)) * 16;   // kk=1

    // ---- prologue: A(0), B(0), B(1); A(1) is staged by tile0's P1/P2 ----
    STAGE_HALF(gA, As0, 0, 0);
    STAGE_HALF(gA, As0, 1, 0);
    STAGE_HALF(gB, Bs0, 0, 0);
    STAGE_HALF(gB, Bs0, 1, 0);
    STAGE_HALF(gB, Bs1, 0, 1);
    STAGE_HALF(gB, Bs1, 1, 1);
    SB();
    asm volatile("s_waitcnt vmcnt(4)" ::: "memory");   // tile0 resident, B(1) in flight
    SB();
    __builtin_amdgcn_s_barrier();
    SB();

#pragma unroll 1
    for (int kt2 = 0; kt2 < 15; ++kt2) {
        do_tile<2>(2 * kt2,     As0, As1, Bs0, gA, gB, w8, rowA, rowB, xg0, xg1, acc);
        do_tile<2>(2 * kt2 + 1, As1, As0, Bs1, gA, gB, w8, rowA, rowB, xg0, xg1, acc);
    }
    do_tile<1>(30, As0, As1, Bs0, gA, gB, w8, rowA, rowB, xg0, xg1, acc);
    do_tile<0>(31, As1, As0, Bs1, gA, gB, w8, rowA, rowB, xg0, xg1, acc);

    // ---------- fused LSTM epilogue (shuffle-free via gate-deinterleave) ----
    // C/D layout: col = lane&15 (n), row = quad*4 + reg (m).
    // N-packing puts gate = nj, h = ((n0+wn*64)>>6)*16 + lane15 for this wave:
    // acc[mi][0..3] are (zf,zi,zo,zc) of the SAME h, for 4 consecutive m rows.
    float biasv[4];
#pragma unroll
    for (int nj = 0; nj < 4; ++nj)
        biasv[nj] = bias[n0 + wn * 64 + nj * 16 + lane15];

    const int hcol = ((n0 + wn * 64) >> 6) * 16 + lane15;   // h index for this lane

#pragma unroll
    for (int mi = 0; mi < 8; ++mi) {
        const int mbase = m0 + wm * 128 + mi * 16 + quad * 4;
        f32x4 zf4 = acc[mi][0];
        f32x4 zi4 = acc[mi][1];
        f32x4 zo4 = acc[mi][2];
        f32x4 zc4 = acc[mi][3];
#pragma unroll
        for (int r = 0; r < 4; ++r) {
            float zf = zf4[r] + biasv[0];
            float zi = zi4[r] + biasv[1];
            float zo = zo4[r] + biasv[2];
            float zc = zc4[r] + biasv[3];

            float gf = fast_sigmoid(zf);
            float gi = fast_sigmoid(zi);
            float go = fast_sigmoid(zo);
            float mh = fast_tanh(zc);

            const size_t off = (size_t)(mbase + r) * DH + hcol;
            float cp = c_prev[off];
            float ct = gf * cp + gi * mh;
            float ht = go * fast_tanh(ct);
            h_out[off] = ht;
            c_out[off] = ct;
        }
    }
}

// ---------- launch ----------
extern "C" void kernel_launch(void* const* d_in, const int* in_sizes, int n_in,
                              void* d_out, int out_size, void* d_ws, size_t ws_size,
                              hipStream_t stream) {
    const float* e_t     = (const float*)d_in[0];
    const float* h_prev  = (const float*)d_in[1];
    const float* c_prev  = (const float*)d_in[2];
    const float* W_x     = (const float*)d_in[3];
    const float* b_x     = (const float*)d_in[4];
    const float* W_h     = (const float*)d_in[5];
    const float* b_h     = (const float*)d_in[6];
    const float* b_extra = (const float*)d_in[7];

    float* h_out = (float*)d_out;
    float* c_out = h_out + (size_t)B_ROWS * DH;

    // workspace layout: A_cat (32MB) | W_cat (16MB) | bias (16KB)
    unsigned short* A_cat = (unsigned short*)d_ws;
    unsigned short* W_cat = (unsigned short*)((char*)d_ws + (size_t)B_ROWS * KTOT * 2);
    float*          bias  = (float*)((char*)d_ws + (size_t)B_ROWS * KTOT * 2 + (size_t)NTOT * KTOT * 2);

    pack_all<<<NBLK_A + NBLK_W + NBLK_BIAS, 256, 0, stream>>>(
        e_t, h_prev, W_x, W_h, b_x, b_h, b_extra, A_cat, W_cat, bias);
    lstm_gemm<<<dim3(NTOT / 256, B_ROWS / 256), 512, 0, stream>>>(
        A_cat, W_cat, bias, c_prev, h_out, c_out);
}

// Round 5
// 299.963 us; speedup vs baseline: 1.0131x; 1.0131x over previous
//
#include <hip/hip_runtime.h>
#include <stdint.h>

// Problem constants (fixed by reference)
#define B_ROWS 8192
#define DH     1024      // D == H == 1024
#define KTOT   2048      // D + H (concatenated K)
#define NTOT   4096      // 4*H columns (gate-deinterleaved packing, see below)

typedef __attribute__((ext_vector_type(8))) __bf16 bf16x8;
typedef __attribute__((ext_vector_type(4))) float  f32x4;

// ---------- helpers ----------
__device__ __forceinline__ unsigned short f2bf(float f) {
    unsigned int u = __float_as_uint(f);
    u += 0x7FFFu + ((u >> 16) & 1u);   // round-to-nearest-even
    return (unsigned short)(u >> 16);
}

__device__ __forceinline__ float fast_sigmoid(float x) {
    return 1.0f / (1.0f + __expf(-x));
}
__device__ __forceinline__ float fast_tanh(float x) {
    float e = __expf(fminf(-2.0f * x, 80.0f));   // clamp avoids inf/inf
    return (1.0f - e) / (1.0f + e);
}

// ---------- single fused pack kernel ----------
// N-space packing (gate-deinterleaved for the shuffle-free epilogue):
//   W_cat row n holds W row g = gate*DH + h with
//     gate = (n>>4) & 3,  h = (n>>6)*16 + (n&15)
//   bias[] packed identically.  The GEMM is invariant to this column perm.
#define NBLK_A (B_ROWS)            // one block packs one 2048-elem row
#define NBLK_W (NTOT)
#define NBLK_BIAS (NTOT / 256)

__global__ __launch_bounds__(256) void pack_all(const float* __restrict__ e_t,
                                                const float* __restrict__ h_prev,
                                                const float* __restrict__ W_x,
                                                const float* __restrict__ W_h,
                                                const float* __restrict__ b_x,
                                                const float* __restrict__ b_h,
                                                const float* __restrict__ b_e,
                                                unsigned short* __restrict__ A_cat,
                                                unsigned short* __restrict__ W_cat,
                                                float* __restrict__ bias) {
    const int blk = blockIdx.x;
    const int t   = threadIdx.x;
    if (blk < NBLK_A + NBLK_W) {
        const float* src0;
        unsigned short* dst;
        int row;
        if (blk < NBLK_A) {
            row = blk;
            dst = A_cat + (size_t)row * KTOT;
            int c8 = t << 3;
            src0 = (c8 < DH) ? (e_t + (size_t)row * DH + c8)
                             : (h_prev + (size_t)row * DH + (c8 - DH));
        } else {
            row = blk - NBLK_A;                 // n in [0,4096)
            int gate = (row >> 4) & 3;
            int h    = (row >> 6) * 16 + (row & 15);
            int srow = gate * DH + h;
            dst = W_cat + (size_t)row * KTOT;
            int c8 = t << 3;
            src0 = (c8 < DH) ? (W_x + (size_t)srow * DH + c8)
                             : (W_h + (size_t)srow * DH + (c8 - DH));
        }
        float4 f0 = ((const float4*)src0)[0];
        float4 f1 = ((const float4*)src0)[1];
        uint4 o;
        o.x = (unsigned)f2bf(f0.x) | ((unsigned)f2bf(f0.y) << 16);
        o.y = (unsigned)f2bf(f0.z) | ((unsigned)f2bf(f0.w) << 16);
        o.z = (unsigned)f2bf(f1.x) | ((unsigned)f2bf(f1.y) << 16);
        o.w = (unsigned)f2bf(f1.z) | ((unsigned)f2bf(f1.w) << 16);
        *(uint4*)(dst + t * 8) = o;
    } else {
        int gp = (blk - NBLK_A - NBLK_W) * 256 + t;   // n in [0,4096)
        int gate = (gp >> 4) & 3;
        int h    = (gp >> 6) * 16 + (gp & 15);
        int g    = gate * DH + h;
        bias[gp] = b_x[g] + b_h[g] + b_e[g];
    }
}

// ---------- 256x256 8-wave GEMM, pipelined counted-lgkmcnt schedule ----------
//
// BM=BN=256, BK=64, 8 waves (2M x 4N), LDS 128 KiB (2-parity A/B buffers).
// XOR granule swizzle (verified): logical 16B-granule g of row r stored at
// physical p = g ^ (r&7); applied on the global SOURCE address; fragment
// reads use p = (kk*4+quad) ^ (lane15&7).
//
// ROUND-5 RESTRUCTURE: R4 measured 5775 cyc/tile = fully SERIAL
// (reads 2260 + MFMA 2483 + GLL 512 + sync).  Cause: every phase waited
// lgkmcnt(0) on reads issued moments before -> LDS pipe and matrix pipe
// alternate.  Fix = issue-early / wait-late with counted lgkmcnt (DS ops
// retire in order), so read service overlaps MFMA execution:
//
//   issue R1 (al0 x4 kk0, b0 x4 kk0)     8 ds_read
//   issue R2 (ah  x4 kk0)                4 ds_read
//   stage A(t+1) h0+h1                   4 GLL -> As_next
//   issue R3 (al1 x4 kk1, b1 x4 kk1)     8 ds_read
//   lgkm(12) -> C1 (al0 x b0)            // waits R1 only; R2,R3 in flight
//   lgkm(8)  -> C2 (ah  x b0)            // waits R2 (serviced under C1)
//   issue R4 (ah x4 kk1; reuses ah regs — C2 already issued)
//   lgkm(4)  -> C3 (al1 x b1)            // waits R3 (serviced under C1+C2)
//   barrier                              // all waves retired B(t) reads
//   stage B(t+2) h0+h1                   4 GLL -> Bs_cur
//   lgkm(0)  -> C4 (ah  x b1)            // waits R4 (serviced under C3)
//   vmcnt(4); barrier                    // per-wave GLL order
//                                        // [B(t+1), A(t+1), B(t+2)]:
//                                        // vmcnt(4) proves tile t+1 resident
//
// 2 barriers/tile (was 8); only R1 (~500cy) exposed, once per tile.
// LIVENESS: A(t+1)->As_next: last read of that parity = R4(t-1), retired
// before t-1's end barrier.  B(t+2)->Bs_cur: b0/b1 reads retired at
// lgkm(4) before the mid-tile barrier.  vmcnt never 0 in the main loop.

#define GLL(srcp, dstp) \
    __builtin_amdgcn_global_load_lds( \
        (const __attribute__((address_space(1))) void*)(srcp), \
        (__attribute__((address_space(3))) void*)(dstp), 16, 0, 0)

// one half-tile = 128 rows x 64 cols bf16 = 2 GLL/wave (8 waves x 64 lanes x 16B)
#define STAGE_HALF(g, buf, h, kt) do { \
    GLL((g) + ((size_t)((h) * 128)      * KTOT) + (size_t)(kt) * 64, (buf) + (((h) * 128)      + w8) * 128); \
    GLL((g) + ((size_t)((h) * 128 + 64) * KTOT) + (size_t)(kt) * 64, (buf) + (((h) * 128 + 64) + w8) * 128); \
} while (0)

#define SB() __builtin_amdgcn_sched_barrier(0)

#define WAIT_LGKM(n) do { SB(); asm volatile("s_waitcnt lgkmcnt(" #n ")" ::: "memory"); SB(); } while (0)

template <int MODE>  // 2 = steady  (stage A(t+1) + B(t+2), vmcnt(4))
                     // 1 = tile 30 (stage A(31) only, vmcnt(0))
                     // 0 = tile 31 (no staging, no vmcnt, no end barrier)
__device__ __forceinline__ void do_tile(
    int kt,
    unsigned char* As_cur, unsigned char* As_next, unsigned char* Bs_cur,
    const unsigned short* __restrict__ gA, const unsigned short* __restrict__ gB,
    int w8, int rowA, int rowB, int xg0, int xg1,
    f32x4 (&acc)[8][4])
{
    bf16x8 al0[4], ah[4], al1[4], b0[4], b1[4];

    // ---- issue R1: A-lo kk0 (4) + B kk0 (4) ----
#pragma unroll
    for (int mi = 0; mi < 4; ++mi)
        al0[mi] = *(const bf16x8*)(As_cur + rowA + mi * 2048 + xg0);
#pragma unroll
    for (int ni = 0; ni < 4; ++ni)
        b0[ni] = *(const bf16x8*)(Bs_cur + rowB + ni * 2048 + xg0);
    // ---- issue R2: A-hi kk0 (4) ----
#pragma unroll
    for (int mi = 0; mi < 4; ++mi)
        ah[mi] = *(const bf16x8*)(As_cur + rowA + (4 + mi) * 2048 + xg0);
    // ---- stage A(t+1) into other parity (safe since t-1's end barrier) ----
    if constexpr (MODE >= 1) {
        STAGE_HALF(gA, As_next, 0, kt + 1);
        STAGE_HALF(gA, As_next, 1, kt + 1);
    }
    // ---- issue R3: A-lo kk1 (4) + B kk1 (4) ----
#pragma unroll
    for (int mi = 0; mi < 4; ++mi)
        al1[mi] = *(const bf16x8*)(As_cur + rowA + mi * 2048 + xg1);
#pragma unroll
    for (int ni = 0; ni < 4; ++ni)
        b1[ni] = *(const bf16x8*)(Bs_cur + rowB + ni * 2048 + xg1);

    // ---- C1: lo x kk0 (waits R1; R2+R3 = 12 stay in flight) ----
    WAIT_LGKM(12);
    __builtin_amdgcn_s_setprio(1);
#pragma unroll
    for (int mi = 0; mi < 4; ++mi)
#pragma unroll
        for (int ni = 0; ni < 4; ++ni)
            acc[mi][ni] = __builtin_amdgcn_mfma_f32_16x16x32_bf16(al0[mi], b0[ni], acc[mi][ni], 0, 0, 0);
    __builtin_amdgcn_s_setprio(0);
    SB();

    // ---- C2: hi x kk0 (waits R2, serviced under C1; R3 = 8 in flight) ----
    WAIT_LGKM(8);
    __builtin_amdgcn_s_setprio(1);
#pragma unroll
    for (int mi = 0; mi < 4; ++mi)
#pragma unroll
        for (int ni = 0; ni < 4; ++ni)
            acc[4 + mi][ni] = __builtin_amdgcn_mfma_f32_16x16x32_bf16(ah[mi], b0[ni], acc[4 + mi][ni], 0, 0, 0);
    __builtin_amdgcn_s_setprio(0);
    SB();

    // ---- issue R4: A-hi kk1 (4); reuses ah regs (C2 already issued) ----
#pragma unroll
    for (int mi = 0; mi < 4; ++mi)
        ah[mi] = *(const bf16x8*)(As_cur + rowA + (4 + mi) * 2048 + xg1);

    // ---- C3: lo x kk1 (waits R3, serviced under C1+C2; R4 in flight) ----
    WAIT_LGKM(4);
    __builtin_amdgcn_s_setprio(1);
#pragma unroll
    for (int mi = 0; mi < 4; ++mi)
#pragma unroll
        for (int ni = 0; ni < 4; ++ni)
            acc[mi][ni] = __builtin_amdgcn_mfma_f32_16x16x32_bf16(al1[mi], b1[ni], acc[mi][ni], 0, 0, 0);
    __builtin_amdgcn_s_setprio(0);
    SB();

    // ---- mid-tile barrier: every wave has retired its B(t) reads ----
    __builtin_amdgcn_s_barrier();
    SB();
    if constexpr (MODE == 2) {
        STAGE_HALF(gB, Bs_cur, 0, kt + 2);
        STAGE_HALF(gB, Bs_cur, 1, kt + 2);
    }

    // ---- C4: hi x kk1 (waits R4, serviced under C3) ----
    WAIT_LGKM(0);
    __builtin_amdgcn_s_setprio(1);
#pragma unroll
    for (int mi = 0; mi < 4; ++mi)
#pragma unroll
        for (int ni = 0; ni < 4; ++ni)
            acc[4 + mi][ni] = __builtin_amdgcn_mfma_f32_16x16x32_bf16(ah[mi], b1[ni], acc[4 + mi][ni], 0, 0, 0);
    __builtin_amdgcn_s_setprio(0);
    SB();

    // ---- tile end: tile t+1 resident before its reads begin ----
    if constexpr (MODE == 2) {
        asm volatile("s_waitcnt vmcnt(4)" ::: "memory");   // retires B(t+1), A(t+1)
        SB();
        __builtin_amdgcn_s_barrier();
        SB();
    } else if constexpr (MODE == 1) {
        asm volatile("s_waitcnt vmcnt(0)" ::: "memory");   // tile 31 resident
        SB();
        __builtin_amdgcn_s_barrier();
        SB();
    }
}

__global__ __launch_bounds__(512, 2) void lstm_gemm(
    const unsigned short* __restrict__ A,
    const unsigned short* __restrict__ Wc,
    const float* __restrict__ bias,
    const float* __restrict__ c_prev,
    float* __restrict__ h_out,
    float* __restrict__ c_out)
{
    __shared__ __align__(16) unsigned char lds[131072];

    const int tid = threadIdx.x;
    const int w   = tid >> 6;          // wave 0..7
    const int l   = tid & 63;          // lane
    const int wm  = w >> 2, wn = w & 3;
    const int m0  = blockIdx.y * 256;
    const int n0  = blockIdx.x * 256;
    const int w8  = w * 8;

    f32x4 acc[8][4];
#pragma unroll
    for (int i = 0; i < 8; ++i)
#pragma unroll
        for (int j = 0; j < 4; ++j) acc[i][j] = {0.f, 0.f, 0.f, 0.f};

    // staging: wave w, lane l -> tile row = base + w*8 + (l>>3),
    // physical granule p = l&7, pre-swizzled source granule g = p ^ (row&7)
    const int srow = w8 + (l >> 3);
    const int scol = ((l & 7) ^ ((l >> 3) & 7)) * 8;   // element offset in 64-wide K-tile
    const unsigned short* gA = A  + (size_t)(m0 + srow) * KTOT + scol;
    const unsigned short* gB = Wc + (size_t)(n0 + srow) * KTOT + scol;

    unsigned char* As0 = lds;
    unsigned char* As1 = lds + 32768;
    unsigned char* Bs0 = lds + 65536;
    unsigned char* Bs1 = lds + 98304;

    const int lane15 = l & 15;
    const int quad   = l >> 4;
    const int rowA = (wm * 128 + lane15) * 128;   // byte offset of A fragment row base
    const int rowB = (wn * 64  + lane15) * 128;
    const int xg0  = ((0 + quad) ^ (lane15 & 7)) * 16;   // kk=0 swizzled granule
    const int xg1  = ((4 + quad) ^ (lane15 & 7)) * 16;   // kk=1

    // ---- prologue: A(0), B(0) resident; B(1) in flight; A(1) staged in tile0 --
    STAGE_HALF(gA, As0, 0, 0);
    STAGE_HALF(gA, As0, 1, 0);
    STAGE_HALF(gB, Bs0, 0, 0);
    STAGE_HALF(gB, Bs0, 1, 0);
    STAGE_HALF(gB, Bs1, 0, 1);
    STAGE_HALF(gB, Bs1, 1, 1);
    SB();
    asm volatile("s_waitcnt vmcnt(4)" ::: "memory");   // A(0),B(0) done; B(1) in flight
    SB();
    __builtin_amdgcn_s_barrier();
    SB();

#pragma unroll 1
    for (int kt2 = 0; kt2 < 15; ++kt2) {
        do_tile<2>(2 * kt2,     As0, As1, Bs0, gA, gB, w8, rowA, rowB, xg0, xg1, acc);
        do_tile<2>(2 * kt2 + 1, As1, As0, Bs1, gA, gB, w8, rowA, rowB, xg0, xg1, acc);
    }
    do_tile<1>(30, As0, As1, Bs0, gA, gB, w8, rowA, rowB, xg0, xg1, acc);
    do_tile<0>(31, As1, As0, Bs1, gA, gB, w8, rowA, rowB, xg0, xg1, acc);

    // ---------- fused LSTM epilogue (shuffle-free via gate-deinterleave) ----
    // C/D layout: col = lane&15 (n), row = quad*4 + reg (m).
    // N-packing puts gate = nj, h = ((n0+wn*64)>>6)*16 + lane15 for this wave:
    // acc[mi][0..3] are (zf,zi,zo,zc) of the SAME h, for 4 consecutive m rows.
    float biasv[4];
#pragma unroll
    for (int nj = 0; nj < 4; ++nj)
        biasv[nj] = bias[n0 + wn * 64 + nj * 16 + lane15];

    const int hcol = ((n0 + wn * 64) >> 6) * 16 + lane15;   // h index for this lane

#pragma unroll
    for (int mi = 0; mi < 8; ++mi) {
        const int mbase = m0 + wm * 128 + mi * 16 + quad * 4;
        f32x4 zf4 = acc[mi][0];
        f32x4 zi4 = acc[mi][1];
        f32x4 zo4 = acc[mi][2];
        f32x4 zc4 = acc[mi][3];
#pragma unroll
        for (int r = 0; r < 4; ++r) {
            float zf = zf4[r] + biasv[0];
            float zi = zi4[r] + biasv[1];
            float zo = zo4[r] + biasv[2];
            float zc = zc4[r] + biasv[3];

            float gf = fast_sigmoid(zf);
            float gi = fast_sigmoid(zi);
            float go = fast_sigmoid(zo);
            float mh = fast_tanh(zc);

            const size_t off = (size_t)(mbase + r) * DH + hcol;
            float cp = c_prev[off];
            float ct = gf * cp + gi * mh;
            float ht = go * fast_tanh(ct);
            h_out[off] = ht;
            c_out[off] = ct;
        }
    }
}

// ---------- launch ----------
extern "C" void kernel_launch(void* const* d_in, const int* in_sizes, int n_in,
                              void* d_out, int out_size, void* d_ws, size_t ws_size,
                              hipStream_t stream) {
    const float* e_t     = (const float*)d_in[0];
    const float* h_prev  = (const float*)d_in[1];
    const float* c_prev  = (const float*)d_in[2];
    const float* W_x     = (const float*)d_in[3];
    const float* b_x     = (const float*)d_in[4];
    const float* W_h     = (const float*)d_in[5];
    const float* b_h     = (const float*)d_in[6];
    const float* b_extra = (const float*)d_in[7];

    float* h_out = (float*)d_out;
    float* c_out = h_out + (size_t)B_ROWS * DH;

    // workspace layout: A_cat (32MB) | W_cat (16MB) | bias (16KB)
    unsigned short* A_cat = (unsigned short*)d_ws;
    unsigned short* W_cat = (unsigned short*)((char*)d_ws + (size_t)B_ROWS * KTOT * 2);
    float*          bias  = (float*)((char*)d_ws + (size_t)B_ROWS * KTOT * 2 + (size_t)NTOT * KTOT * 2);

    pack_all<<<NBLK_A + NBLK_W + NBLK_BIAS, 256, 0, stream>>>(
        e_t, h_prev, W_x, W_h, b_x, b_h, b_extra, A_cat, W_cat, bias);
    lstm_gemm<<<dim3(NTOT / 256, B_ROWS / 256), 512, 0, stream>>>(
        A_cat, W_cat, bias, c_prev, h_out, c_out);
}